// Round 2
// 1154.100 us; speedup vs baseline: 2.1851x; 2.1851x over previous
//
#include <hip/hip_runtime.h>
#include <hip/hip_bf16.h>
#include <math.h>

#define B_ 2048
#define L_ 32
#define V_ 1024
#define E_ 256
#define H_ 512
#define DEC_T_ 7

typedef unsigned short u16;
typedef unsigned int u32;
using bf16x8 = __attribute__((ext_vector_type(8))) short;
using f32x4  = __attribute__((ext_vector_type(4))) float;

__device__ __forceinline__ u16 f2b(float f) {
  union { float f; u32 i; } x; x.f = f;
  u32 r = x.i + 0x7FFFu + ((x.i >> 16) & 1u);
  return (u16)(r >> 16);
}
__device__ __forceinline__ float b2f(u16 u) {
  union { u32 i; float f; } x; x.i = ((u32)u) << 16; return x.f;
}
__device__ __forceinline__ float sigm(float x) { return 1.f / (1.f + __expf(-x)); }
__device__ __forceinline__ float tanhfast(float x) {
  const float xx = fminf(fmaxf(x, -15.f), 15.f);
  const float e = __expf(2.f * xx);
  return (e - 1.f) / (e + 1.f);
}

// async global->LDS, 16B per lane. dest = wave-uniform base + lane*16.
__device__ __forceinline__ void gl_lds16(const void* g, void* l) {
  __builtin_amdgcn_global_load_lds((const __attribute__((address_space(1))) u32*)g,
                                   (__attribute__((address_space(3))) u32*)l, 16, 0, 0);
}

// ---------------------------------------------------------------------------
// Tile layout (both GEMM kernels): LDS tiles [128 rows][32 bf16] linear
// (64B rows), double-buffered. 16B chunks are XOR-swizzled: logical chunk c of
// row r lives at physical chunk c ^ ((r>>1)&3). Staged via global_load_lds
// with the XOR applied to the per-lane GLOBAL source chunk (linear LDS dest),
// read back with the same XOR on the ds_read address (both-sides involution).
// 16 lanes reading logical chunk c across rows r0..r0+15 then hit all 32
// banks exactly 2x (free) vs an 8-way conflict unswizzled.
// ---------------------------------------------------------------------------

// Fused transposed LSTM gate GEMM: G^T[j][m] = sum_k W[j][k]*act[m][k].
// act = [emb_bf16[tok] | h_bf16] (encoder, K=768) or h_bf16 (decoder, K=512).
// Cell update fused in epilogue; h stored bf16, c fp32 transposed [H][B].
struct LP {
  const int* feat;      // token ptr (pre-offset by step); null => decoder
  const u16* emb;       // V x E bf16
  const u16* h_in;      // B x H bf16
  const u16* W;         // 2048 x K bf16, gate-interleaved rows
  const float* bsum;    // 2048 fp32
  u16* h_out;           // B x H bf16
  float* c;             // H x B fp32 transposed, in-place
  int K;
};

__launch_bounds__(256)
__global__ void lstm_mfma_k(LP p0, LP p1) {
  __shared__ u16 Wt[2][128 * 32];
  __shared__ u16 At[2][128 * 32];
  const int tid = threadIdx.x;
  const int lane = tid & 63, wave = tid >> 6;
  const int wr = wave & 1, wc = wave >> 1;

  // XCD-contiguous swizzle: XCD x gets gridDim/8 consecutive logical ids.
  const int q = gridDim.x >> 3;
  const int bid = blockIdx.x;
  const int id2 = (bid & 7) * q + (bid >> 3);
  LP p = (id2 >= 256) ? p1 : p0;
  const int jm = id2 & 255;
  const int j0 = (jm >> 4) * 128, m0 = (jm & 15) * 128;
  const int lr = lane & 15;
  const int swk = ((lane >> 4) ^ ((lane >> 1) & 3)) * 8;   // swizzled read chunk

  // staging: wave stages rows [wave*32, wave*32+32) of both tiles
  const int srow = wave * 32 + (lane >> 2);
  const int csrc = ((lane & 3) ^ ((lane >> 3) & 3)) * 8;   // swizzled src chunk
  const u16* wsrc0 = p.W + (j0 + srow) * p.K + csrc;
  const u16* wsrc1 = wsrc0 + 16 * p.K;
  const u16* hsrc0 = p.h_in + (m0 + srow) * H_ + csrc;
  const u16* hsrc1 = hsrc0 + 16 * H_;
  const u16* esrc0 = nullptr; const u16* esrc1 = nullptr;
  const int koff = p.feat ? E_ : 0;
  if (p.feat) {                      // hoist token gather out of K-loop
    const int t0 = p.feat[(m0 + srow) * L_];
    const int t1 = p.feat[(m0 + srow + 16) * L_];
    esrc0 = p.emb + t0 * E_ + csrc;
    esrc1 = p.emb + t1 * E_ + csrc;
  }
  u16* wdst0 = &Wt[0][(wave * 32) * 32];
  u16* wdst1 = wdst0 + 16 * 32;
  u16* adst0 = &At[0][(wave * 32) * 32];
  u16* adst1 = adst0 + 16 * 32;

  f32x4 acc[4][4] = {};
  const int NT = p.K >> 5;

  auto stage = [&](int kt, int buf) {
    const int k0 = kt << 5;
    const int bo = buf * (128 * 32);
    gl_lds16(wsrc0 + k0, wdst0 + bo);
    gl_lds16(wsrc1 + k0, wdst1 + bo);
    if (k0 < koff) {
      gl_lds16(esrc0 + k0, adst0 + bo);
      gl_lds16(esrc1 + k0, adst1 + bo);
    } else {
      gl_lds16(hsrc0 + (k0 - koff), adst0 + bo);
      gl_lds16(hsrc1 + (k0 - koff), adst1 + bo);
    }
  };

  stage(0, 0);
  __syncthreads();                    // drains vmcnt -> buf0 ready
  int cur = 0;
  for (int kt = 0; kt < NT; ++kt) {
    if (kt + 1 < NT) stage(kt + 1, cur ^ 1);   // prefetch overlaps MFMA below
    const u16* Wb = &Wt[cur][0];
    const u16* Ab = &At[cur][0];
    bf16x8 af[4], bb[4];
#pragma unroll
    for (int t = 0; t < 4; ++t) {
      af[t] = *(const bf16x8*)(Wb + (wr * 64 + t * 16 + lr) * 32 + swk);
      bb[t] = *(const bf16x8*)(Ab + (wc * 64 + t * 16 + lr) * 32 + swk);
    }
#pragma unroll
    for (int i = 0; i < 4; ++i)
#pragma unroll
      for (int j = 0; j < 4; ++j)
        acc[i][j] = __builtin_amdgcn_mfma_f32_16x16x32_bf16(af[i], bb[j], acc[i][j], 0, 0, 0);
    __syncthreads();                  // vmcnt(0): prefetched buf ready
    cur ^= 1;
  }

  // epilogue: lane's 4 regs = gates i,f,g,o of hidden unit n, batch col m
#pragma unroll
  for (int i = 0; i < 4; ++i) {
    const int jb = j0 + wr * 64 + i * 16 + (lane >> 4) * 4;
    const int n = jb >> 2;
    const float4 bs = *(const float4*)(p.bsum + jb);
#pragma unroll
    for (int j = 0; j < 4; ++j) {
      const int m = m0 + wc * 64 + j * 16 + lr;
      const int cidx = n * B_ + m;          // c transposed -> coalesced
      const float gi = acc[i][j][0] + bs.x;
      const float gf = acc[i][j][1] + bs.y;
      const float gg = acc[i][j][2] + bs.z;
      const float go = acc[i][j][3] + bs.w;
      const float cn = sigm(gf) * p.c[cidx] + sigm(gi) * tanhfast(gg);
      const float hn = sigm(go) * tanhfast(cn);
      p.c[cidx] = cn;
      p.h_out[m * H_ + n] = f2b(hn);
    }
  }
}

// ---------------------------------------------------------------------------
// Plain bf16 GEMM + bias: C[m][v] = A[m]*W[v] + bias[v], fp32 out.
// ldc==0 => ff mode: row m encodes (t=m>>11, b=m&2047), C index b*7V+t*V+v.
// ---------------------------------------------------------------------------
struct OP {
  const u16* A;       // M x K bf16
  const u16* W;       // N x K bf16
  const float* bias;  // N fp32
  float* Cf;
  int ldc;            // 0 => ff (t,b) mode
  int K;
};

__launch_bounds__(256)
__global__ void out_mfma_k(OP p0, OP p1) {
  OP p = blockIdx.z ? p1 : p0;
  __shared__ u16 Ws[2][128 * 32];
  __shared__ u16 As[2][128 * 32];
  const int tid = threadIdx.x;
  const int lane = tid & 63, wave = tid >> 6;
  const int wr = wave & 1, wc = wave >> 1;
  const int v0 = blockIdx.x * 128, m0 = blockIdx.y * 128;
  const int lr = lane & 15;
  const int swk = ((lane >> 4) ^ ((lane >> 1) & 3)) * 8;

  const int srow = wave * 32 + (lane >> 2);
  const int csrc = ((lane & 3) ^ ((lane >> 3) & 3)) * 8;
  const u16* wsrc0 = p.W + (v0 + srow) * p.K + csrc;
  const u16* wsrc1 = wsrc0 + 16 * p.K;
  const u16* asrc0 = p.A + (m0 + srow) * p.K + csrc;
  const u16* asrc1 = asrc0 + 16 * p.K;
  u16* wdst0 = &Ws[0][(wave * 32) * 32];
  u16* wdst1 = wdst0 + 16 * 32;
  u16* adst0 = &As[0][(wave * 32) * 32];
  u16* adst1 = adst0 + 16 * 32;

  f32x4 acc[4][4] = {};
  const int NT = p.K >> 5;

  auto stage = [&](int kt, int buf) {
    const int k0 = kt << 5;
    const int bo = buf * (128 * 32);
    gl_lds16(wsrc0 + k0, wdst0 + bo);
    gl_lds16(wsrc1 + k0, wdst1 + bo);
    gl_lds16(asrc0 + k0, adst0 + bo);
    gl_lds16(asrc1 + k0, adst1 + bo);
  };

  stage(0, 0);
  __syncthreads();
  int cur = 0;
  for (int kt = 0; kt < NT; ++kt) {
    if (kt + 1 < NT) stage(kt + 1, cur ^ 1);
    const u16* Wb = &Ws[cur][0];
    const u16* Ab = &As[cur][0];
    bf16x8 aa[4], bb[4];
#pragma unroll
    for (int t = 0; t < 4; ++t) {
      aa[t] = *(const bf16x8*)(Ab + (wr * 64 + t * 16 + lr) * 32 + swk);
      bb[t] = *(const bf16x8*)(Wb + (wc * 64 + t * 16 + lr) * 32 + swk);
    }
#pragma unroll
    for (int i = 0; i < 4; ++i)
#pragma unroll
      for (int j = 0; j < 4; ++j)
        acc[i][j] = __builtin_amdgcn_mfma_f32_16x16x32_bf16(aa[i], bb[j], acc[i][j], 0, 0, 0);
    __syncthreads();
    cur ^= 1;
  }

#pragma unroll
  for (int j = 0; j < 4; ++j) {
    const int v = v0 + wc * 64 + j * 16 + lr;
    const float bv = p.bias[v];
#pragma unroll
    for (int i = 0; i < 4; ++i) {
      const int mb = m0 + wr * 64 + i * 16 + (lane >> 4) * 4;
#pragma unroll
      for (int r = 0; r < 4; ++r) {
        const int m = mb + r;
        const float val = acc[i][j][r] + bv;
        if (p.ldc) p.Cf[m * p.ldc + v] = val;
        else p.Cf[(m & (B_ - 1)) * (DEC_T_ * V_) + (m >> 11) * V_ + v] = val;
      }
    }
  }
}

// ---- prep: gate-interleaved bf16 weight + combined bias ---------------------
__global__ void prep_gates_k(const float* Wih, const float* Whh,
                             const float* b1, const float* b2,
                             u16* Wout, float* bsum, int KI, int K) {
  const int j = blockIdx.y;
  const int k = blockIdx.x * 256 + threadIdx.x;
  const int worig = (j & 3) * H_ + (j >> 2);
  const float v = (k < KI) ? Wih[worig * KI + k] : Whh[worig * H_ + (k - KI)];
  Wout[(long)j * K + k] = f2b(v);
  if (k == 0) bsum[j] = b1[worig] + b2[worig];
}

__global__ void cast_k(const float* s, u16* d) {
  const int i = blockIdx.x * 256 + threadIdx.x;
  d[i] = f2b(s[i]);
}

__global__ void init_k(u16* a, u16* b, float* c, float* d) {
  const int i = blockIdx.x * 256 + threadIdx.x;
  a[i] = 0; b[i] = 0; c[i] = 0.f; d[i] = 0.f;
}

__global__ void cast_feat_k(const int* f, float* o) {
  const int i = blockIdx.x * 256 + threadIdx.x;
  o[i] = b2f(f2b((float)f[i]));
}

// fused LN stats + apply (both param sets), bf16 in/out
__global__ void ln_k(const u16* hf, const u16* hb,
                     const float* g0, const float* b0,
                     const float* g1, const float* b1,
                     u16* A0, u16* A1) {
  const int b = blockIdx.x, t = threadIdx.x;
  const int k4 = t * 4;
  const u16* src = (k4 < H_) ? (hf + b * H_ + k4) : (hb + b * H_ + (k4 - H_));
  const ushort4 raw = *(const ushort4*)src;
  const float x0 = b2f(raw.x), x1 = b2f(raw.y), x2 = b2f(raw.z), x3 = b2f(raw.w);
  float s = x0 + x1 + x2 + x3;
  float sq = x0 * x0 + x1 * x1 + x2 * x2 + x3 * x3;
#pragma unroll
  for (int off = 32; off; off >>= 1) {
    s += __shfl_down(s, off);
    sq += __shfl_down(sq, off);
  }
  __shared__ float ss[4], ssq[4], smv[2];
  if ((t & 63) == 0) { ss[t >> 6] = s; ssq[t >> 6] = sq; }
  __syncthreads();
  if (t == 0) {
    const float S = ss[0] + ss[1] + ss[2] + ss[3];
    const float SQ = ssq[0] + ssq[1] + ssq[2] + ssq[3];
    const float m = S * (1.f / 1024.f);
    const float var = SQ * (1.f / 1024.f) - m * m;
    smv[0] = m; smv[1] = rsqrtf(var + 1e-5f);
  }
  __syncthreads();
  const float m = smv[0], rs = smv[1];
  const float4 ga = *(const float4*)(g0 + k4), ba = *(const float4*)(b0 + k4);
  const float4 gb = *(const float4*)(g1 + k4), bb = *(const float4*)(b1 + k4);
  ushort4 o0, o1;
  o0.x = f2b((x0 - m) * rs * ga.x + ba.x);
  o0.y = f2b((x1 - m) * rs * ga.y + ba.y);
  o0.z = f2b((x2 - m) * rs * ga.z + ba.z);
  o0.w = f2b((x3 - m) * rs * ga.w + ba.w);
  o1.x = f2b((x0 - m) * rs * gb.x + bb.x);
  o1.y = f2b((x1 - m) * rs * gb.y + bb.y);
  o1.z = f2b((x2 - m) * rs * gb.z + bb.z);
  o1.w = f2b((x3 - m) * rs * gb.w + bb.w);
  *(ushort4*)(A0 + b * 1024 + k4) = o0;
  *(ushort4*)(A1 + b * 1024 + k4) = o1;
}

__global__ void z_k(const float* mu, const float* lv, const float* eps,
                    u16* dz, float* dc) {
  const int i = blockIdx.x * 256 + threadIdx.x;
  const float z = mu[i] + __expf(0.5f * lv[i]) * eps[i];
  dz[i] = f2b(z);
  dc[(i & (H_ - 1)) * B_ + (i >> 9)] = z;   // c transposed [H][B]
}

extern "C" void kernel_launch(void* const* d_in, const int* in_sizes, int n_in,
                              void* d_out, int out_size, void* d_ws, size_t ws_size,
                              hipStream_t stream) {
  const int*   features = (const int*)d_in[0];
  const float* eps      = (const float*)d_in[1];
  const float* emb      = (const float*)d_in[2];
  const float* eWih_f   = (const float*)d_in[3];
  const float* eWhh_f   = (const float*)d_in[4];
  const float* ebih_f   = (const float*)d_in[5];
  const float* ebhh_f   = (const float*)d_in[6];
  const float* eWih_b   = (const float*)d_in[7];
  const float* eWhh_b   = (const float*)d_in[8];
  const float* ebih_b   = (const float*)d_in[9];
  const float* ebhh_b   = (const float*)d_in[10];
  const float* dWhh     = (const float*)d_in[12];
  const float* dbih     = (const float*)d_in[13];
  const float* dbhh     = (const float*)d_in[14];
  const float* mu_ln_g  = (const float*)d_in[15];
  const float* mu_ln_b  = (const float*)d_in[16];
  const float* mu_W     = (const float*)d_in[17];
  const float* mu_b     = (const float*)d_in[18];
  const float* lv_ln_g  = (const float*)d_in[19];
  const float* lv_ln_b  = (const float*)d_in[20];
  const float* lv_W     = (const float*)d_in[21];
  const float* lv_b     = (const float*)d_in[22];
  const float* ff_W     = (const float*)d_in[23];
  const float* ff_b     = (const float*)d_in[24];

  float* of = (float*)d_out;
  float* o_feat = of;
  float* o_fh   = of + (B_ * L_);
  float* o_mu   = o_fh + (long)B_ * DEC_T_ * V_;
  float* o_lv   = o_mu + (long)B_ * H_;

  const int NA = B_ * H_;
  // ---- ws layout: 33.5 MB total (< 35 MB proven-safe bound) ----------------
  // Persistent:  [0-2M) hfa  [2-4M) hba  (final enc h)
  // Enc-phase:   [4-6M) hfb  [6-8M) hbb  (ping)  [8-12M) cf  [12-16M) cb
  //              [16-22M) Wenc_f/b
  // Persistent:  [22-27.5M) Wdec,Wff,Wmu,Wlv,embb  + bsums
  //              [~27.55-29.55M) dz   [29.55-33.55M) dc
  // Post-enc aliases (regions dead by then):
  //   An0 = [4-8M) (hfb+hbb), An1 = [8-12M) (cf)   — LN'd acts
  //   dech = [4-18M) (hfb..cb + first 2M of Wenc_f) — decoder h history
  u16* hfa = (u16*)d_ws;
  u16* hba = hfa + NA;
  u16* hfb = hba + NA;
  u16* hbb = hfb + NA;
  float* cf = (float*)(hbb + NA);
  float* cb = cf + NA;
  u16* Wenc_f = (u16*)(cb + NA);            // 2048*768
  u16* Wenc_b = Wenc_f + 2048 * 768;        // 2048*768
  u16* Wdec   = Wenc_b + 2048 * 768;        // 2048*512
  u16* Wff    = Wdec + 2048 * 512;          // 1024*512
  u16* Wmu    = Wff + 1024 * 512;           // 512*1024
  u16* Wlv    = Wmu + 512 * 1024;           // 512*1024
  u16* embb   = Wlv + 512 * 1024;           // 1024*256
  float* bsum_f = (float*)(embb + V_ * E_); // 3 x 2048 fp32
  float* bsum_b = bsum_f + 2048;
  float* bsum_d = bsum_b + 2048;
  u16* dz     = (u16*)(bsum_d + 2048);      // B*H bf16
  float* dc   = (float*)(dz + NA);          // H x B fp32 (dec c, transposed)
  u16* An0    = hfb;                        // alias: 4 MB over hfb+hbb
  u16* An1    = (u16*)cf;                   // alias: 4 MB over cf
  u16* dech   = hfb;                        // alias: 14 MB over hfb..Wenc_f[:2M]

  cast_feat_k<<<dim3(B_ * L_ / 256), dim3(256), 0, stream>>>(features, o_feat);
  init_k<<<dim3(NA / 256), dim3(256), 0, stream>>>(hfa, hba, cf, cb);

  prep_gates_k<<<dim3(3, 2048), dim3(256), 0, stream>>>(eWih_f, eWhh_f, ebih_f, ebhh_f, Wenc_f, bsum_f, E_, E_ + H_);
  prep_gates_k<<<dim3(3, 2048), dim3(256), 0, stream>>>(eWih_b, eWhh_b, ebih_b, ebhh_b, Wenc_b, bsum_b, E_, E_ + H_);
  prep_gates_k<<<dim3(2, 2048), dim3(256), 0, stream>>>(nullptr, dWhh, dbih, dbhh, Wdec, bsum_d, 0, H_);
  cast_k<<<dim3(1024 * 512 / 256), dim3(256), 0, stream>>>(ff_W, Wff);
  cast_k<<<dim3(512 * 1024 / 256), dim3(256), 0, stream>>>(mu_W, Wmu);
  cast_k<<<dim3(512 * 1024 / 256), dim3(256), 0, stream>>>(lv_W, Wlv);
  cast_k<<<dim3(V_ * E_ / 256), dim3(256), 0, stream>>>(emb, embb);

  // ---- encoder: 32 dual-direction fused MFMA steps -------------------------
  for (int s = 0; s < L_; ++s) {
    LP pf{}, pb{};
    pf.feat = features + s;              pb.feat = features + (L_ - 1 - s);
    pf.emb = embb;                       pb.emb = embb;
    pf.h_in  = (s & 1) ? hfb : hfa;      pb.h_in  = (s & 1) ? hbb : hba;
    pf.h_out = (s & 1) ? hfa : hfb;      pb.h_out = (s & 1) ? hba : hbb;
    pf.W = Wenc_f;  pf.bsum = bsum_f;    pb.W = Wenc_b;  pb.bsum = bsum_b;
    pf.c = cf;                           pb.c = cb;
    pf.K = E_ + H_;                      pb.K = E_ + H_;
    lstm_mfma_k<<<dim3(512), dim3(256), 0, stream>>>(pf, pb);
  }
  // 32 (even) steps: final fwd h in hfa, bwd h in hba.

  // ---- LN (fused stats+apply) + mu/lv heads --------------------------------
  ln_k<<<dim3(B_), dim3(256), 0, stream>>>(hfa, hba, mu_ln_g, mu_ln_b, lv_ln_g, lv_ln_b, An0, An1);
  {
    OP pm{}, pl{};
    pm.A = An0; pm.W = Wmu; pm.bias = mu_b; pm.Cf = o_mu; pm.ldc = H_; pm.K = 2 * H_;
    pl = pm;
    pl.A = An1; pl.W = Wlv; pl.bias = lv_b; pl.Cf = o_lv;
    out_mfma_k<<<dim3(4, 16, 2), dim3(256), 0, stream>>>(pm, pl);
  }
  z_k<<<dim3(NA / 256), dim3(256), 0, stream>>>(o_mu, o_lv, eps, dz, dc);

  // ---- decoder: 7 fused MFMA steps, then ONE batched ff GEMM ---------------
  for (int t = 0; t < DEC_T_; ++t) {
    LP pg{};
    pg.feat = nullptr; pg.emb = nullptr;
    pg.h_in  = t ? (dech + (long)(t - 1) * NA) : dz;
    pg.h_out = dech + (long)t * NA;
    pg.W = Wdec; pg.bsum = bsum_d;
    pg.c = dc;
    pg.K = H_;
    lstm_mfma_k<<<dim3(256), dim3(256), 0, stream>>>(pg, pg);
  }
  {
    OP po{};
    po.A = dech; po.W = Wff; po.bias = ff_b;
    po.Cf = o_fh; po.ldc = 0;            // ff (t,b) mode
    po.K = H_;
    out_mfma_k<<<dim3(8, DEC_T_ * 16, 1), dim3(256), 0, stream>>>(po, po);
  }
}